// Round 1
// baseline (304.227 us; speedup 1.0000x reference)
//
#include <hip/hip_runtime.h>
#include <stdint.h>

typedef _Float16 f16;
typedef _Float16 f16x4 __attribute__((ext_vector_type(4)));
typedef _Float16 f16x8 __attribute__((ext_vector_type(8)));
typedef float f32x4 __attribute__((ext_vector_type(4)));

#define LOG2E 1.44269504088896340736f

__device__ __forceinline__ f32x4 mfma_16x16x32(f16x8 a, f16x8 b, f32x4 c) {
    return __builtin_amdgcn_mfma_f32_16x16x32_f16(a, b, c, 0, 0, 0);
}

__device__ __forceinline__ void gload_lds16(const void* g, void* l) {
    __builtin_amdgcn_global_load_lds(
        (const __attribute__((address_space(1))) unsigned int*)g,
        (__attribute__((address_space(3))) unsigned int*)l, 16, 0, 0);
}

// ---------------- cast f32 -> f16, 4 elements/thread ----------------
__global__ void cast_f32_f16(const float* __restrict__ src, f16* __restrict__ dst, int n4) {
    int i = blockIdx.x * 256 + threadIdx.x;
    if (i >= n4) return;
    float4 v = reinterpret_cast<const float4*>(src)[i];
    f16x4 o;
    o[0] = (f16)v.x; o[1] = (f16)v.y; o[2] = (f16)v.z; o[3] = (f16)v.w;
    reinterpret_cast<f16x4*>(dst)[i] = o;
}

// ---------------- TN GEMM: C[M][N] = A[M][K] * W[N][K]^T + bias ----------------
// MODE 0: scatter to Q/K/V f16 buffers [B=4][H=16][T=2048][D=64], Q scaled by 0.125
// MODE 1: f32 output [M][N] with bias
template<int MODE>
__global__ __launch_bounds__(256, 2)
void gemm_tn(const f16* __restrict__ A, const f16* __restrict__ W,
             const float* __restrict__ bias, void* __restrict__ outp,
             int M, int N, int K)
{
    __shared__ __align__(16) f16 As[128 * 32];
    __shared__ __align__(16) f16 Bs[128 * 32];

    const int lane = threadIdx.x & 63;
    const int wave = threadIdx.x >> 6;
    const int l15 = lane & 15, l4 = lane >> 4;
    const int row0 = blockIdx.y * 128;
    const int col0 = blockIdx.x * 128;
    const int wr = wave >> 1, wc = wave & 1;

    f32x4 acc[4][4] = {};

    const int srow = lane >> 2;        // row within 16-row chunk
    const int scol = (lane & 3) * 8;   // element offset in 32-elem K row

    for (int k0 = 0; k0 < K; k0 += 32) {
        __syncthreads();
        #pragma unroll
        for (int it = 0; it < 2; ++it) {
            int chunk = it * 4 + wave;
            const f16* gA = A + (size_t)(row0 + chunk * 16 + srow) * K + k0 + scol;
            gload_lds16(gA, As + chunk * 512);
            const f16* gB = W + (size_t)(col0 + chunk * 16 + srow) * K + k0 + scol;
            gload_lds16(gB, Bs + chunk * 512);
        }
        __syncthreads();   // drains vmcnt: staged data visible

        f16x8 af[4], bf[4];
        #pragma unroll
        for (int m = 0; m < 4; ++m)
            af[m] = *reinterpret_cast<const f16x8*>(As + (wr * 64 + m * 16 + l15) * 32 + l4 * 8);
        #pragma unroll
        for (int n = 0; n < 4; ++n)
            bf[n] = *reinterpret_cast<const f16x8*>(Bs + (wc * 64 + n * 16 + l15) * 32 + l4 * 8);
        #pragma unroll
        for (int m = 0; m < 4; ++m)
            #pragma unroll
            for (int n = 0; n < 4; ++n)
                acc[m][n] = mfma_16x16x32(af[m], bf[n], acc[m][n]);
    }

    // C/D layout (m89-verified): col = lane&15, row = (lane>>4)*4 + reg
    if (MODE == 0) {
        f16* qb = (f16*)outp;
        const size_t HS = (size_t)64 * 2048 * 64;   // 8388608 elems per tensor
        #pragma unroll
        for (int m = 0; m < 4; ++m) {
            int rbase = row0 + wr * 64 + m * 16 + l4 * 4;
            #pragma unroll
            for (int n = 0; n < 4; ++n) {
                int j = col0 + wc * 64 + n * 16 + l15;
                int which = j >> 10;          // 0=q 1=k 2=v
                int h = (j >> 6) & 15;
                int d = j & 63;
                float bj = bias[j];
                f16* base = qb + (size_t)which * HS;
                float scale = (which == 0) ? 0.125f : 1.0f;   // fold 1/sqrt(64) into Q
                #pragma unroll
                for (int r = 0; r < 4; ++r) {
                    int row = rbase + r;
                    int b = row >> 11, t = row & 2047;
                    size_t off = ((size_t)(b * 16 + h) * 2048 + t) * 64 + d;
                    base[off] = (f16)((acc[m][n][r] + bj) * scale);
                }
            }
        }
    } else {
        float* O = (float*)outp;
        #pragma unroll
        for (int m = 0; m < 4; ++m) {
            int rbase = row0 + wr * 64 + m * 16 + l4 * 4;
            #pragma unroll
            for (int n = 0; n < 4; ++n) {
                int j = col0 + wc * 64 + n * 16 + l15;
                float bj = bias[j];
                #pragma unroll
                for (int r = 0; r < 4; ++r)
                    O[(size_t)(rbase + r) * N + j] = acc[m][n][r] + bj;
            }
        }
    }
}

// ---------------- flash attention, causal ----------------
// grid: (bh=64, qblk=32), block 256 = 4 waves; each wave owns 16 q-rows.
__global__ __launch_bounds__(256, 2)
void attn_kernel(const f16* __restrict__ qb, const f16* __restrict__ kb,
                 const f16* __restrict__ vb, f16* __restrict__ ob)
{
    __shared__ __align__(16) f16 Ks[64 * 64];      // [key][d], col16 XOR-swizzled
    __shared__ __align__(16) f16 Vs[64][72];       // [d][key] transposed, padded
    __shared__ __align__(16) f16 Ps[4][16][72];    // per-wave P tile

    const int bh = blockIdx.x;       // b*16 + h
    const int qblk = blockIdx.y;
    const int lane = threadIdx.x & 63;
    const int wave = threadIdx.x >> 6;
    const int l15 = lane & 15, l4 = lane >> 4;
    const int q0 = qblk * 64;

    // Q A-frag: row = lane&15, d = kc*32 + (lane>>4)*8 + i  (Q pre-scaled by 0.125)
    const f16* Qp = qb + ((size_t)bh * 2048 + q0 + wave * 16) * 64;
    f16x8 aq[2];
    aq[0] = *reinterpret_cast<const f16x8*>(Qp + l15 * 64 + l4 * 8);
    aq[1] = *reinterpret_cast<const f16x8*>(Qp + l15 * 64 + 32 + l4 * 8);

    float Mr[4], Lr[4];
    f32x4 oacc[4] = {};
    #pragma unroll
    for (int r = 0; r < 4; ++r) { Mr[r] = -1e30f; Lr[r] = 0.0f; }

    for (int kv0 = 0; kv0 <= q0; kv0 += 64) {
        __syncthreads();   // previous tile's LDS reads done

        // stage K (8KB contiguous) with source-side XOR swizzle: LDS[row][c] = K[row][c ^ (row&7)]
        const f16* Kt = kb + ((size_t)bh * 2048 + kv0) * 64;
        #pragma unroll
        for (int it = 0; it < 2; ++it) {
            int c = it * 4 + wave;
            int p = c * 1024 + lane * 16;      // linear LDS byte
            int krow = p >> 7;
            int col16 = (p >> 4) & 7;
            int s16 = col16 ^ (krow & 7);
            gload_lds16(Kt + krow * 64 + s16 * 8, Ks + c * 512);
        }
        // stage V transposed into padded LDS
        const f16* Vt = vb + ((size_t)bh * 2048 + kv0) * 64;
        #pragma unroll
        for (int it = 0; it < 2; ++it) {
            int p = it * 256 + (int)threadIdx.x;   // 16B-unit index 0..511
            int key = p >> 3;
            int d0 = (p & 7) * 8;
            f16x8 v = *reinterpret_cast<const f16x8*>(Vt + key * 64 + d0);
            #pragma unroll
            for (int e = 0; e < 8; ++e)
                Vs[d0 + e][key] = v[e];
        }
        __syncthreads();

        const bool diag = (kv0 == q0);

        // S = Q * K^T  (16 rows x 64 keys per wave)
        f32x4 s[4];
        #pragma unroll
        for (int n = 0; n < 4; ++n) {
            int key = n * 16 + l15;
            f32x4 c = {};
            #pragma unroll
            for (int kc = 0; kc < 2; ++kc) {
                int colb = (kc * 4 + l4) ^ (key & 7);
                f16x8 bk = *reinterpret_cast<const f16x8*>(Ks + key * 64 + colb * 8);
                c = mfma_16x16x32(aq[kc], bk, c);
            }
            s[n] = c;
        }

        // online softmax, wave-parallel (rows live across 16-lane groups)
        float alpha[4];
        #pragma unroll
        for (int r = 0; r < 4; ++r) {
            int qrow = q0 + wave * 16 + l4 * 4 + r;
            float mx = -1e30f;
            #pragma unroll
            for (int n = 0; n < 4; ++n) {
                if (diag && (kv0 + n * 16 + l15 > qrow)) s[n][r] = -1e30f;
                mx = fmaxf(mx, s[n][r]);
            }
            #pragma unroll
            for (int sh = 1; sh <= 8; sh <<= 1)
                mx = fmaxf(mx, __shfl_xor(mx, sh));
            float nm = fmaxf(Mr[r], mx);
            alpha[r] = exp2f((Mr[r] - nm) * LOG2E);
            Mr[r] = nm;
            float rs = 0.0f;
            #pragma unroll
            for (int n = 0; n < 4; ++n) {
                float pv = exp2f((s[n][r] - nm) * LOG2E);
                s[n][r] = pv;
                rs += pv;
            }
            #pragma unroll
            for (int sh = 1; sh <= 8; sh <<= 1)
                rs += __shfl_xor(rs, sh);
            Lr[r] = Lr[r] * alpha[r] + rs;
        }

        // P -> per-wave LDS (re-fragment for PV A-operand)
        #pragma unroll
        for (int n = 0; n < 4; ++n)
            #pragma unroll
            for (int r = 0; r < 4; ++r)
                Ps[wave][l4 * 4 + r][n * 16 + l15] = (f16)s[n][r];

        #pragma unroll
        for (int dt = 0; dt < 4; ++dt) {
            oacc[dt][0] *= alpha[0]; oacc[dt][1] *= alpha[1];
            oacc[dt][2] *= alpha[2]; oacc[dt][3] *= alpha[3];
        }

        // PV: O += P[16x64] * V[64x64]
        f16x8 pa0 = *reinterpret_cast<const f16x8*>(&Ps[wave][l15][l4 * 8]);
        f16x8 pa1 = *reinterpret_cast<const f16x8*>(&Ps[wave][l15][32 + l4 * 8]);
        #pragma unroll
        for (int dt = 0; dt < 4; ++dt) {
            int d = dt * 16 + l15;
            f16x8 v0 = *reinterpret_cast<const f16x8*>(&Vs[d][l4 * 8]);
            f16x8 v1 = *reinterpret_cast<const f16x8*>(&Vs[d][32 + l4 * 8]);
            oacc[dt] = mfma_16x16x32(pa0, v0, oacc[dt]);
            oacc[dt] = mfma_16x16x32(pa1, v1, oacc[dt]);
        }
    }

    // normalize + store to [B][T][H*64+d] f16
    const int b = bh >> 4, h = bh & 15;
    f16* O = ob + ((size_t)b * 2048 + q0 + wave * 16) * 1024 + h * 64;
    #pragma unroll
    for (int dt = 0; dt < 4; ++dt) {
        int d = dt * 16 + l15;
        #pragma unroll
        for (int r = 0; r < 4; ++r) {
            int row = l4 * 4 + r;
            O[(size_t)row * 1024 + d] = (f16)(oacc[dt][r] / Lr[r]);
        }
    }
}

extern "C" void kernel_launch(void* const* d_in, const int* in_sizes, int n_in,
                              void* d_out, int out_size, void* d_ws, size_t ws_size,
                              hipStream_t stream)
{
    const float* x    = (const float*)d_in[0];
    const float* qkvw = (const float*)d_in[1];
    const float* qkvb = (const float*)d_in[2];
    const float* outw = (const float*)d_in[3];
    const float* outb = (const float*)d_in[4];
    float* out = (float*)d_out;

    // ws layout (f16): x_h 16.8MB | qkvw_h 6.3MB | outw_h 2.1MB | q/k/v 3x16.8MB | att_o 16.8MB  (~92MB)
    f16* x_h    = (f16*)d_ws;
    f16* qkvw_h = x_h + (size_t)8192 * 1024;
    f16* outw_h = qkvw_h + (size_t)3072 * 1024;
    f16* q_buf  = outw_h + (size_t)1024 * 1024;
    f16* att_o  = q_buf + (size_t)3 * 8388608;

    cast_f32_f16<<<8192, 256, 0, stream>>>(x, x_h, 2097152);
    cast_f32_f16<<<3072, 256, 0, stream>>>(qkvw, qkvw_h, 786432);
    cast_f32_f16<<<1024, 256, 0, stream>>>(outw, outw_h, 262144);

    gemm_tn<0><<<dim3(24, 64), 256, 0, stream>>>(x_h, qkvw_h, qkvb, q_buf, 8192, 3072, 1024);
    attn_kernel<<<dim3(64, 32), 256, 0, stream>>>(q_buf, q_buf + 8388608, q_buf + 2 * 8388608, att_o);
    gemm_tn<1><<<dim3(8, 64), 256, 0, stream>>>(att_o, outw_h, outb, out, 8192, 1024, 1024);
}

// Round 2
// 202.169 us; speedup vs baseline: 1.5048x; 1.5048x over previous
//
#include <hip/hip_runtime.h>
#include <stdint.h>

typedef _Float16 f16;
typedef _Float16 f16x4 __attribute__((ext_vector_type(4)));
typedef _Float16 f16x8 __attribute__((ext_vector_type(8)));
typedef float f32x4 __attribute__((ext_vector_type(4)));

#define LOG2E 1.44269504088896340736f

__device__ __forceinline__ f32x4 mfma_16x16x32(f16x8 a, f16x8 b, f32x4 c) {
    return __builtin_amdgcn_mfma_f32_16x16x32_f16(a, b, c, 0, 0, 0);
}

__device__ __forceinline__ void gload_lds16(const void* g, void* l) {
    __builtin_amdgcn_global_load_lds(
        (const __attribute__((address_space(1))) unsigned int*)g,
        (__attribute__((address_space(3))) unsigned int*)l, 16, 0, 0);
}

// ---------------- cast f32 -> f16, 4 elements/thread ----------------
__global__ void cast_f32_f16(const float* __restrict__ src, f16* __restrict__ dst, int n4) {
    int i = blockIdx.x * 256 + threadIdx.x;
    if (i >= n4) return;
    float4 v = reinterpret_cast<const float4*>(src)[i];
    f16x4 o;
    o[0] = (f16)v.x; o[1] = (f16)v.y; o[2] = (f16)v.z; o[3] = (f16)v.w;
    reinterpret_cast<f16x4*>(dst)[i] = o;
}

// ---------------- TN GEMM: C[M][N] = A[M][K] * W[N][K]^T + bias ----------------
// MODE 0: scatter to Q/K/V f16 buffers [B=4][H=16][T=2048][D=64], Q scaled by 0.125*log2(e)
// MODE 1: f32 output [M][N] with bias
template<int MODE>
__global__ __launch_bounds__(256, 2)
void gemm_tn(const f16* __restrict__ A, const f16* __restrict__ W,
             const float* __restrict__ bias, void* __restrict__ outp,
             int M, int N, int K)
{
    __shared__ __align__(16) f16 As[128 * 32];
    __shared__ __align__(16) f16 Bs[128 * 32];

    const int lane = threadIdx.x & 63;
    const int wave = threadIdx.x >> 6;
    const int l15 = lane & 15, l4 = lane >> 4;
    const int row0 = blockIdx.y * 128;
    const int col0 = blockIdx.x * 128;
    const int wr = wave >> 1, wc = wave & 1;

    f32x4 acc[4][4] = {};

    const int srow = lane >> 2;        // row within 16-row chunk
    const int scol = (lane & 3) * 8;   // element offset in 32-elem K row

    for (int k0 = 0; k0 < K; k0 += 32) {
        __syncthreads();
        #pragma unroll
        for (int it = 0; it < 2; ++it) {
            int chunk = it * 4 + wave;
            const f16* gA = A + (size_t)(row0 + chunk * 16 + srow) * K + k0 + scol;
            gload_lds16(gA, As + chunk * 512);
            const f16* gB = W + (size_t)(col0 + chunk * 16 + srow) * K + k0 + scol;
            gload_lds16(gB, Bs + chunk * 512);
        }
        __syncthreads();   // drains vmcnt: staged data visible

        f16x8 af[4], bf[4];
        #pragma unroll
        for (int m = 0; m < 4; ++m)
            af[m] = *reinterpret_cast<const f16x8*>(As + (wr * 64 + m * 16 + l15) * 32 + l4 * 8);
        #pragma unroll
        for (int n = 0; n < 4; ++n)
            bf[n] = *reinterpret_cast<const f16x8*>(Bs + (wc * 64 + n * 16 + l15) * 32 + l4 * 8);
        #pragma unroll
        for (int m = 0; m < 4; ++m)
            #pragma unroll
            for (int n = 0; n < 4; ++n)
                acc[m][n] = mfma_16x16x32(af[m], bf[n], acc[m][n]);
    }

    // C/D layout (m89-verified): col = lane&15, row = (lane>>4)*4 + reg
    if (MODE == 0) {
        f16* qb = (f16*)outp;
        const size_t HS = (size_t)64 * 2048 * 64;   // 8388608 elems per tensor
        #pragma unroll
        for (int m = 0; m < 4; ++m) {
            int rbase = row0 + wr * 64 + m * 16 + l4 * 4;
            #pragma unroll
            for (int n = 0; n < 4; ++n) {
                int j = col0 + wc * 64 + n * 16 + l15;
                int which = j >> 10;          // 0=q 1=k 2=v
                int h = (j >> 6) & 15;
                int d = j & 63;
                float bj = bias[j];
                f16* base = qb + (size_t)which * HS;
                // fold 1/sqrt(64) AND log2(e) into Q so attention uses exp2 directly
                float scale = (which == 0) ? (0.125f * LOG2E) : 1.0f;
                #pragma unroll
                for (int r = 0; r < 4; ++r) {
                    int row = rbase + r;
                    int b = row >> 11, t = row & 2047;
                    size_t off = ((size_t)(b * 16 + h) * 2048 + t) * 64 + d;
                    base[off] = (f16)((acc[m][n][r] + bj) * scale);
                }
            }
        }
    } else {
        float* O = (float*)outp;
        #pragma unroll
        for (int m = 0; m < 4; ++m) {
            int rbase = row0 + wr * 64 + m * 16 + l4 * 4;
            #pragma unroll
            for (int n = 0; n < 4; ++n) {
                int j = col0 + wc * 64 + n * 16 + l15;
                float bj = bias[j];
                #pragma unroll
                for (int r = 0; r < 4; ++r)
                    O[(size_t)(rbase + r) * N + j] = acc[m][n][r] + bj;
            }
        }
    }
}

// ---------------- flash attention, causal, swapped-QK^T ----------------
// grid: (bh=64, qblk=32 reversed), block 256 = 4 waves; each wave owns 16 q-rows.
// S^T = mfma(K_frag, Q_frag): each lane holds S[q=lane&15][16 keys] -> in-lane softmax.
__global__ __launch_bounds__(256, 2)
void attn_kernel(const f16* __restrict__ qb, const f16* __restrict__ kb,
                 const f16* __restrict__ vb, f16* __restrict__ ob)
{
    __shared__ __align__(16) f16 Ks[64 * 64];      // [key][d], 16B-chunk XOR-swizzled
    __shared__ __align__(16) f16 Vs[64][72];       // [d][key] transposed, padded
    __shared__ __align__(16) f16 Ps[4][16][72];    // per-wave P tile [q][key]

    const int bh = blockIdx.x;                         // b*16 + h
    const int qblk = (int)gridDim.y - 1 - (int)blockIdx.y;  // longest blocks first
    const int lane = threadIdx.x & 63;
    const int wave = threadIdx.x >> 6;
    const int l15 = lane & 15, l4 = lane >> 4;
    const int q0 = qblk * 64;

    // Q B-frag: col=q=lane&15, k(d) = kc*32 + (lane>>4)*8 + i   (Q pre-scaled)
    const f16* Qp = qb + ((size_t)bh * 2048 + q0 + wave * 16) * 64;
    f16x8 aq[2];
    aq[0] = *reinterpret_cast<const f16x8*>(Qp + l15 * 64 + l4 * 8);
    aq[1] = *reinterpret_cast<const f16x8*>(Qp + l15 * 64 + 32 + l4 * 8);

    float Mr = -1e30f, Lr = 0.0f;
    f32x4 oacc[4] = {};

    for (int kv0 = 0; kv0 <= q0; kv0 += 64) {
        __syncthreads();   // previous tile's LDS reads done

        // stage K with source-side XOR swizzle: LDS chunk c of row = K chunk c^(row&7)
        const f16* Kt = kb + ((size_t)bh * 2048 + kv0) * 64;
        #pragma unroll
        for (int it = 0; it < 2; ++it) {
            int c = it * 4 + wave;
            int p = c * 1024 + lane * 16;      // linear LDS byte
            int krow = p >> 7;
            int col16 = (p >> 4) & 7;
            int s16 = col16 ^ (krow & 7);
            gload_lds16(Kt + krow * 64 + s16 * 8, Ks + c * 512);
        }
        // stage V transposed: key = lane (bank = lane>>1 spans all banks, 2-way = free)
        const f16* Vt = vb + ((size_t)bh * 2048 + kv0) * 64;
        {
            const int d0 = wave * 16;
            #pragma unroll
            for (int it = 0; it < 2; ++it) {
                f16x8 v = *reinterpret_cast<const f16x8*>(Vt + lane * 64 + d0 + it * 8);
                #pragma unroll
                for (int e = 0; e < 8; ++e)
                    Vs[d0 + it * 8 + e][lane] = v[e];
            }
        }
        __syncthreads();

        const bool diag = (kv0 == q0);

        // S^T = K * Q^T: acc col = q = l15, row = key_local = n*16 + l4*4 + r
        f32x4 s[4];
        #pragma unroll
        for (int n = 0; n < 4; ++n) {
            int key = n * 16 + l15;
            int cs = key & 7;
            f32x4 c = {};
            #pragma unroll
            for (int kc = 0; kc < 2; ++kc) {
                f16x8 kf = *reinterpret_cast<const f16x8*>(Ks + key * 64 + (((kc * 4 + l4) ^ cs) * 8));
                c = mfma_16x16x32(kf, aq[kc], c);
            }
            s[n] = c;
        }

        if (diag) {
            #pragma unroll
            for (int n = 0; n < 4; ++n)
                #pragma unroll
                for (int r = 0; r < 4; ++r)
                    if (n * 16 + l4 * 4 + r > wave * 16 + l15) s[n][r] = -1e30f;
        }

        // in-lane softmax for q-row l15 (values already in log2 domain)
        float mx = -1e30f;
        #pragma unroll
        for (int n = 0; n < 4; ++n)
            #pragma unroll
            for (int r = 0; r < 4; ++r)
                mx = fmaxf(mx, s[n][r]);
        mx = fmaxf(mx, __shfl_xor(mx, 16));
        mx = fmaxf(mx, __shfl_xor(mx, 32));
        float nm = fmaxf(Mr, mx);
        float alpha = exp2f(Mr - nm);
        Mr = nm;

        float rs = 0.0f;
        #pragma unroll
        for (int n = 0; n < 4; ++n) {
            f16x4 pk;
            #pragma unroll
            for (int r = 0; r < 4; ++r) {
                float pv = exp2f(s[n][r] - nm);
                rs += pv;
                pk[r] = (f16)pv;
            }
            *reinterpret_cast<f16x4*>(&Ps[wave][l15][n * 16 + l4 * 4]) = pk;
        }
        rs += __shfl_xor(rs, 16);
        rs += __shfl_xor(rs, 32);
        Lr = Lr * alpha + rs;

        // broadcast alpha from q-row lanes (l15=q') to accumulator rows (q = l4*4+r)
        float ar[4];
        #pragma unroll
        for (int r = 0; r < 4; ++r) ar[r] = __shfl(alpha, l4 * 4 + r);
        #pragma unroll
        for (int dt = 0; dt < 4; ++dt) {
            oacc[dt][0] *= ar[0]; oacc[dt][1] *= ar[1];
            oacc[dt][2] *= ar[2]; oacc[dt][3] *= ar[3];
        }

        // PV: O += P[16x64] * V[64x64]  (same-wave LDS write->read, no barrier needed)
        f16x8 pa0 = *reinterpret_cast<const f16x8*>(&Ps[wave][l15][l4 * 8]);
        f16x8 pa1 = *reinterpret_cast<const f16x8*>(&Ps[wave][l15][32 + l4 * 8]);
        #pragma unroll
        for (int dt = 0; dt < 4; ++dt) {
            int d = dt * 16 + l15;
            f16x8 v0 = *reinterpret_cast<const f16x8*>(&Vs[d][l4 * 8]);
            f16x8 v1 = *reinterpret_cast<const f16x8*>(&Vs[d][32 + l4 * 8]);
            oacc[dt] = mfma_16x16x32(pa0, v0, oacc[dt]);
            oacc[dt] = mfma_16x16x32(pa1, v1, oacc[dt]);
        }
    }

    // normalize + store to [B][T][H*64+d] f16
    float lr[4];
    #pragma unroll
    for (int r = 0; r < 4; ++r) lr[r] = __shfl(Lr, l4 * 4 + r);

    const int b = bh >> 4, h = bh & 15;
    f16* O = ob + ((size_t)b * 2048 + q0 + wave * 16) * 1024 + h * 64;
    #pragma unroll
    for (int dt = 0; dt < 4; ++dt) {
        int d = dt * 16 + l15;
        #pragma unroll
        for (int r = 0; r < 4; ++r)
            O[(size_t)(l4 * 4 + r) * 1024 + d] = (f16)(oacc[dt][r] / lr[r]);
    }
}

extern "C" void kernel_launch(void* const* d_in, const int* in_sizes, int n_in,
                              void* d_out, int out_size, void* d_ws, size_t ws_size,
                              hipStream_t stream)
{
    const float* x    = (const float*)d_in[0];
    const float* qkvw = (const float*)d_in[1];
    const float* qkvb = (const float*)d_in[2];
    const float* outw = (const float*)d_in[3];
    const float* outb = (const float*)d_in[4];
    float* out = (float*)d_out;

    // ws layout (f16): x_h 16.8MB | qkvw_h 6.3MB | outw_h 2.1MB | q/k/v 3x16.8MB | att_o 16.8MB
    f16* x_h    = (f16*)d_ws;
    f16* qkvw_h = x_h + (size_t)8192 * 1024;
    f16* outw_h = qkvw_h + (size_t)3072 * 1024;
    f16* q_buf  = outw_h + (size_t)1024 * 1024;
    f16* att_o  = q_buf + (size_t)3 * 8388608;

    cast_f32_f16<<<8192, 256, 0, stream>>>(x, x_h, 2097152);
    cast_f32_f16<<<3072, 256, 0, stream>>>(qkvw, qkvw_h, 786432);
    cast_f32_f16<<<1024, 256, 0, stream>>>(outw, outw_h, 262144);

    gemm_tn<0><<<dim3(24, 64), 256, 0, stream>>>(x_h, qkvw_h, qkvb, q_buf, 8192, 3072, 1024);
    attn_kernel<<<dim3(64, 32), 256, 0, stream>>>(q_buf, q_buf + 8388608, q_buf + 2 * 8388608, att_o);
    gemm_tn<1><<<dim3(8, 64), 256, 0, stream>>>(att_o, outw_h, outb, out, 8192, 1024, 1024);
}

// Round 4
// 197.366 us; speedup vs baseline: 1.5414x; 1.0243x over previous
//
#include <hip/hip_runtime.h>
#include <stdint.h>

typedef _Float16 f16;
typedef _Float16 f16x2 __attribute__((ext_vector_type(2)));
typedef _Float16 f16x4 __attribute__((ext_vector_type(4)));
typedef _Float16 f16x8 __attribute__((ext_vector_type(8)));
typedef float f32x4 __attribute__((ext_vector_type(4)));

#define LOG2E 1.44269504088896340736f

__device__ __forceinline__ f32x4 mfma_16x16x32(f16x8 a, f16x8 b, f32x4 c) {
    return __builtin_amdgcn_mfma_f32_16x16x32_f16(a, b, c, 0, 0, 0);
}

__device__ __forceinline__ void gload_lds16(const void* g, void* l) {
    __builtin_amdgcn_global_load_lds(
        (const __attribute__((address_space(1))) unsigned int*)g,
        (__attribute__((address_space(3))) unsigned int*)l, 16, 0, 0);
}

__device__ __forceinline__ f16x2 cvt_pk_f16(float a, float b) {
    return __builtin_bit_cast(f16x2, __builtin_amdgcn_cvt_pkrtz(a, b));
}

// ---------------- cast f32 -> f16, 4 elements/thread ----------------
__global__ void cast_f32_f16(const float* __restrict__ src, f16* __restrict__ dst, int n4) {
    int i = blockIdx.x * 256 + threadIdx.x;
    if (i >= n4) return;
    float4 v = reinterpret_cast<const float4*>(src)[i];
    f16x4 o;
    o[0] = (f16)v.x; o[1] = (f16)v.y; o[2] = (f16)v.z; o[3] = (f16)v.w;
    reinterpret_cast<f16x4*>(dst)[i] = o;
}

// ---------------- TN GEMM: C[M][N] = A[M][K] * W[N][K]^T + bias ----------------
// MODE 0: scatter to Q/K/V f16 buffers [B=4][H=16][T=2048][D=64], Q scaled by 0.125*log2(e)
// MODE 1: f32 output [M][N] with bias
template<int MODE>
__global__ __launch_bounds__(256, 2)
void gemm_tn(const f16* __restrict__ A, const f16* __restrict__ W,
             const float* __restrict__ bias, void* __restrict__ outp,
             int M, int N, int K)
{
    __shared__ __align__(16) f16 As[128 * 32];
    __shared__ __align__(16) f16 Bs[128 * 32];

    const int lane = threadIdx.x & 63;
    const int wave = threadIdx.x >> 6;
    const int l15 = lane & 15, l4 = lane >> 4;

    // bijective XCD swizzle (T1): contiguous work chunk per XCD
    const int nwg = (int)(gridDim.x * gridDim.y);
    int orig = (int)(blockIdx.y * gridDim.x + blockIdx.x);
    int cpx = nwg >> 3;                       // grids are multiples of 8
    int w = (orig & 7) * cpx + (orig >> 3);
    const int row0 = (w / (int)gridDim.x) * 128;
    const int col0 = (w % (int)gridDim.x) * 128;
    const int wr = wave >> 1, wc = wave & 1;

    f32x4 acc[4][4] = {};

    const int srow = lane >> 2;        // row within 16-row chunk
    const int scol = (lane & 3) * 8;   // element offset in 32-elem K row

    for (int k0 = 0; k0 < K; k0 += 32) {
        __syncthreads();
        #pragma unroll
        for (int it = 0; it < 2; ++it) {
            int chunk = it * 4 + wave;
            const f16* gA = A + (size_t)(row0 + chunk * 16 + srow) * K + k0 + scol;
            gload_lds16(gA, As + chunk * 512);
            const f16* gB = W + (size_t)(col0 + chunk * 16 + srow) * K + k0 + scol;
            gload_lds16(gB, Bs + chunk * 512);
        }
        __syncthreads();

        f16x8 af[4], bf[4];
        #pragma unroll
        for (int m = 0; m < 4; ++m)
            af[m] = *reinterpret_cast<const f16x8*>(As + (wr * 64 + m * 16 + l15) * 32 + l4 * 8);
        #pragma unroll
        for (int n = 0; n < 4; ++n)
            bf[n] = *reinterpret_cast<const f16x8*>(Bs + (wc * 64 + n * 16 + l15) * 32 + l4 * 8);
        #pragma unroll
        for (int m = 0; m < 4; ++m)
            #pragma unroll
            for (int n = 0; n < 4; ++n)
                acc[m][n] = mfma_16x16x32(af[m], bf[n], acc[m][n]);
    }

    // C/D layout: col = lane&15, row = (lane>>4)*4 + reg
    if (MODE == 0) {
        f16* qb = (f16*)outp;
        const size_t HS = (size_t)64 * 2048 * 64;
        #pragma unroll
        for (int m = 0; m < 4; ++m) {
            int rbase = row0 + wr * 64 + m * 16 + l4 * 4;
            #pragma unroll
            for (int n = 0; n < 4; ++n) {
                int j = col0 + wc * 64 + n * 16 + l15;
                int which = j >> 10;          // 0=q 1=k 2=v
                int h = (j >> 6) & 15;
                int d = j & 63;
                float bj = bias[j];
                f16* base = qb + (size_t)which * HS;
                float scale = (which == 0) ? (0.125f * LOG2E) : 1.0f;
                #pragma unroll
                for (int r = 0; r < 4; ++r) {
                    int row = rbase + r;
                    int b = row >> 11, t = row & 2047;
                    size_t off = ((size_t)(b * 16 + h) * 2048 + t) * 64 + d;
                    base[off] = (f16)((acc[m][n][r] + bj) * scale);
                }
            }
        }
    } else {
        float* O = (float*)outp;
        #pragma unroll
        for (int m = 0; m < 4; ++m) {
            int rbase = row0 + wr * 64 + m * 16 + l4 * 4;
            #pragma unroll
            for (int n = 0; n < 4; ++n) {
                int j = col0 + wc * 64 + n * 16 + l15;
                float bj = bias[j];
                #pragma unroll
                for (int r = 0; r < 4; ++r)
                    O[(size_t)(rbase + r) * N + j] = acc[m][n][r] + bj;
            }
        }
    }
}

// ---------------- flash attention, causal, swapped-QK^T, 32 q-rows/wave ----------------
// grid: (bh=64, qblk=16 reversed), block 256 = 4 waves; wave owns 32 q-rows (2 groups of 16).
// K/V fragments register-cached across both groups.
__global__ __launch_bounds__(256, 3)
void attn_kernel(const f16* __restrict__ qb, const f16* __restrict__ kb,
                 const f16* __restrict__ vb, f16* __restrict__ ob)
{
    __shared__ __align__(16) f16 Ks[64 * 64];      // [key][d], 16B-chunk XOR-swizzled
    __shared__ __align__(16) f16 Vs[64][72];       // [d][key] transposed, padded
    __shared__ __align__(16) f16 Ps[4][16][72];    // per-wave P tile [q][key], reused per group

    const int tid = (int)threadIdx.x;
    const int bh = (int)blockIdx.x;                      // b*16 + h
    const int qblk = (int)gridDim.y - 1 - (int)blockIdx.y;
    const int lane = tid & 63;
    const int wave = tid >> 6;
    const int l15 = lane & 15, l4 = lane >> 4;
    const int q0 = qblk * 128;
    const int qw = q0 + wave * 32;                 // wave's first q-row

    // Q B-frags for both groups: col=q=lane&15, k(d) = kc*32 + (lane>>4)*8 + j (Q pre-scaled)
    const f16* Qp = qb + ((size_t)bh * 2048 + qw) * 64;
    f16x8 aq[2][2];
    #pragma unroll
    for (int g = 0; g < 2; ++g)
        #pragma unroll
        for (int kc = 0; kc < 2; ++kc)
            aq[g][kc] = *reinterpret_cast<const f16x8*>(Qp + (g * 16 + l15) * 64 + kc * 32 + l4 * 8);

    float Mr[2] = {-1e30f, -1e30f}, Lr[2] = {0.0f, 0.0f};
    f32x4 oacc[2][4] = {};

    const int ntiles = q0 / 64 + 2;                // covers keys up to q0+127

    for (int t = 0; t < ntiles; ++t) {
        const int kv0 = t * 64;
        __syncthreads();   // previous tile's LDS reads done

        // ---- stage K (8KB): 512 16B-chunks over 256 threads, XOR-swizzled source ----
        const f16* Kt = kb + ((size_t)bh * 2048 + kv0) * 64;
        #pragma unroll
        for (int it = 0; it < 2; ++it) {
            int c = it * 256 + tid;                // chunk id 0..511
            int krow = c >> 3;
            int s16 = (c & 7) ^ (krow & 7);
            // LDS dest must be wave-uniform base (+ lane*16B implicit)
            gload_lds16(Kt + krow * 64 + s16 * 8, Ks + it * 2048 + wave * 512);
        }
        // ---- stage V transposed (bank-safe: key = lane spans banks, d wave-uniform) ----
        const f16* Vt = vb + ((size_t)bh * 2048 + kv0) * 64;
        #pragma unroll
        for (int it = 0; it < 2; ++it) {
            int dblk = wave * 2 + it;              // wave-uniform d-block
            f16x8 v = *reinterpret_cast<const f16x8*>(Vt + lane * 64 + dblk * 8);
            #pragma unroll
            for (int e = 0; e < 8; ++e)
                Vs[dblk * 8 + e][lane] = v[e];
        }
        __syncthreads();

        // ---- K fragments (A-op, row=key=n*16+l15), V fragments (B-op, col=d=dt*16+l15) ----
        f16x8 kf[4][2], vf[4][2];
        #pragma unroll
        for (int n = 0; n < 4; ++n) {
            int key = n * 16 + l15;
            #pragma unroll
            for (int kc = 0; kc < 2; ++kc)
                kf[n][kc] = *reinterpret_cast<const f16x8*>(Ks + key * 64 + (((kc * 4 + l4) ^ (key & 7)) * 8));
        }
        #pragma unroll
        for (int dt = 0; dt < 4; ++dt) {
            int d = dt * 16 + l15;
            #pragma unroll
            for (int kc = 0; kc < 2; ++kc)
                vf[dt][kc] = *reinterpret_cast<const f16x8*>(&Vs[d][kc * 32 + l4 * 8]);
        }

        #pragma unroll
        for (int g = 0; g < 2; ++g) {
            const int qbase = qw + g * 16;
            if (kv0 > qbase + 15) continue;        // fully masked for this group (wave-uniform)

            // S^T = K * Q^T: col = q = l15, row = key_local = n*16 + l4*4 + r
            f32x4 s[4];
            __builtin_amdgcn_s_setprio(1);
            #pragma unroll
            for (int n = 0; n < 4; ++n) {
                f32x4 c = {};
                c = mfma_16x16x32(kf[n][0], aq[g][0], c);
                c = mfma_16x16x32(kf[n][1], aq[g][1], c);
                s[n] = c;
            }
            __builtin_amdgcn_s_setprio(0);

            if (kv0 + 63 > qbase) {                // diagonal tile: causal mask
                #pragma unroll
                for (int n = 0; n < 4; ++n)
                    #pragma unroll
                    for (int r = 0; r < 4; ++r)
                        if (kv0 + n * 16 + l4 * 4 + r > qbase + l15) s[n][r] = -1e30f;
            }

            // in-lane softmax for q-row l15 (log2 domain)
            float mx = -1e30f;
            #pragma unroll
            for (int n = 0; n < 4; ++n)
                #pragma unroll
                for (int r = 0; r < 4; ++r)
                    mx = fmaxf(mx, s[n][r]);
            mx = fmaxf(mx, __shfl_xor(mx, 16));
            mx = fmaxf(mx, __shfl_xor(mx, 32));
            float nm = fmaxf(Mr[g], mx);
            float alpha = exp2f(Mr[g] - nm);
            Mr[g] = nm;

            float rs = 0.0f;
            #pragma unroll
            for (int n = 0; n < 4; ++n) {
                float p0 = exp2f(s[n][0] - nm);
                float p1 = exp2f(s[n][1] - nm);
                float p2 = exp2f(s[n][2] - nm);
                float p3 = exp2f(s[n][3] - nm);
                rs += (p0 + p1) + (p2 + p3);
                f16x2 lo = cvt_pk_f16(p0, p1);
                f16x2 hi = cvt_pk_f16(p2, p3);
                f16x4 pk; pk[0] = lo[0]; pk[1] = lo[1]; pk[2] = hi[0]; pk[3] = hi[1];
                *reinterpret_cast<f16x4*>(&Ps[wave][l15][n * 16 + l4 * 4]) = pk;
            }
            rs += __shfl_xor(rs, 16);
            rs += __shfl_xor(rs, 32);
            Lr[g] = Lr[g] * alpha + rs;

            // broadcast alpha to accumulator rows (q_local = l4*4+r)
            float ar[4];
            #pragma unroll
            for (int r = 0; r < 4; ++r) ar[r] = __shfl(alpha, l4 * 4 + r);
            #pragma unroll
            for (int dt = 0; dt < 4; ++dt) {
                oacc[g][dt][0] *= ar[0]; oacc[g][dt][1] *= ar[1];
                oacc[g][dt][2] *= ar[2]; oacc[g][dt][3] *= ar[3];
            }

            // PV: O_g += P[16x64] * V[64x64]  (same-wave LDS write->read)
            f16x8 pa0 = *reinterpret_cast<const f16x8*>(&Ps[wave][l15][l4 * 8]);
            f16x8 pa1 = *reinterpret_cast<const f16x8*>(&Ps[wave][l15][32 + l4 * 8]);
            __builtin_amdgcn_s_setprio(1);
            #pragma unroll
            for (int dt = 0; dt < 4; ++dt) {
                oacc[g][dt] = mfma_16x16x32(pa0, vf[dt][0], oacc[g][dt]);
                oacc[g][dt] = mfma_16x16x32(pa1, vf[dt][1], oacc[g][dt]);
            }
            __builtin_amdgcn_s_setprio(0);
        }
    }

    // normalize + store to [B][T][H*64+d] f16
    const int b = bh >> 4, h = bh & 15;
    #pragma unroll
    for (int g = 0; g < 2; ++g) {
        float lr[4];
        #pragma unroll
        for (int r = 0; r < 4; ++r) lr[r] = __shfl(Lr[g], l4 * 4 + r);
        f16* O = ob + ((size_t)b * 2048 + qw + g * 16) * 1024 + h * 64;
        #pragma unroll
        for (int dt = 0; dt < 4; ++dt) {
            int d = dt * 16 + l15;
            #pragma unroll
            for (int r = 0; r < 4; ++r)
                O[(size_t)(l4 * 4 + r) * 1024 + d] = (f16)(oacc[g][dt][r] / lr[r]);
        }
    }
}

extern "C" void kernel_launch(void* const* d_in, const int* in_sizes, int n_in,
                              void* d_out, int out_size, void* d_ws, size_t ws_size,
                              hipStream_t stream)
{
    const float* x    = (const float*)d_in[0];
    const float* qkvw = (const float*)d_in[1];
    const float* qkvb = (const float*)d_in[2];
    const float* outw = (const float*)d_in[3];
    const float* outb = (const float*)d_in[4];
    float* out = (float*)d_out;

    f16* x_h    = (f16*)d_ws;
    f16* qkvw_h = x_h + (size_t)8192 * 1024;
    f16* outw_h = qkvw_h + (size_t)3072 * 1024;
    f16* q_buf  = outw_h + (size_t)1024 * 1024;
    f16* att_o  = q_buf + (size_t)3 * 8388608;

    cast_f32_f16<<<8192, 256, 0, stream>>>(x, x_h, 2097152);
    cast_f32_f16<<<3072, 256, 0, stream>>>(qkvw, qkvw_h, 786432);
    cast_f32_f16<<<1024, 256, 0, stream>>>(outw, outw_h, 262144);

    gemm_tn<0><<<dim3(24, 64), 256, 0, stream>>>(x_h, qkvw_h, qkvb, q_buf, 8192, 3072, 1024);
    attn_kernel<<<dim3(64, 16), 256, 0, stream>>>(q_buf, q_buf + 8388608, q_buf + 2 * 8388608, att_o);
    gemm_tn<1><<<dim3(8, 64), 256, 0, stream>>>(att_o, outw_h, outb, out, 8192, 1024, 1024);
}